// Round 8
// baseline (63.558 us; speedup 1.0000x reference)
//
#include <hip/hip_runtime.h>
#include <hip/hip_bf16.h>
#include <cstdint>

#define N_NODES 4096
#define FIN     128
#define FOUT    64
#define NHEAD   8
#define C_TOT   512   // NHEAD*FOUT
#define ECAP    192   // per-row edge capacity (= 3*64; mean deg ~82, sigma ~9)
#define LDK     136   // padded K-stride (bf16 elems)

typedef float fx4    __attribute__((ext_vector_type(4)));
typedef short bf16x8 __attribute__((ext_vector_type(8)));
typedef float f32x4  __attribute__((ext_vector_type(4)));

__device__ __forceinline__ float lrelu(float v){ return v > 0.f ? v : 0.2f*v; }

__device__ __forceinline__ ushort f2b(float f){
    uint u = __float_as_uint(f);
    return (ushort)((u + 0x7FFFu + ((u >> 16) & 1u)) >> 16);
}

__device__ __forceinline__ float rdlane(float v, int l){
    return __int_as_float(__builtin_amdgcn_readlane(__float_as_int(v), l));
}

// ---------------------------------------------------------------------------
// Kernel 1: MFMA bf16 GEMM (R6-proven). grid (64, 9), 256 thr (4 waves).
//   y = 0..7 : p-head GEMM + svec epilogue + bf16 head-minor store pb[n][c][h]
//   y = 8    : skip GEMM with inline head-averaged skip_w (f32 out, stride 64)
// ---------------------------------------------------------------------------
__global__ __launch_bounds__(256) void k_gemm(const float* __restrict__ x,
        const float* __restrict__ proj, const float* __restrict__ skip_w,
        const float* __restrict__ a_src, const float* __restrict__ a_tgt,
        __hip_bfloat16* __restrict__ pb, float* __restrict__ s_src_t,
        float* __restrict__ s_tgt_t, float* __restrict__ skipbar){
    __shared__ ushort xs[64*LDK];   // A tile
    __shared__ ushort bs[64*LDK];   // B^T tile
    int tid = threadIdx.x;
    int n0  = blockIdx.x * 64;
    int h   = blockIdx.y;

    #pragma unroll
    for (int k=0; k<8; k++){
        int q = tid + k*256;
        int r = q >> 5, f0 = (q & 31)*4;
        float4 v = *(const float4*)(x + (size_t)(n0+r)*FIN + f0);
        ushort4 u = make_ushort4(f2b(v.x), f2b(v.y), f2b(v.z), f2b(v.w));
        *(ushort4*)(xs + r*LDK + f0) = u;
    }
    if (h < 8){
        const float* B = proj + (size_t)h*FIN*FOUT;
        #pragma unroll
        for (int k=0; k<8; k++){
            int q = tid + k*256;
            int f = q >> 4, o0 = (q & 15)*4;
            float4 v = *(const float4*)(B + f*64 + o0);
            bs[(o0+0)*LDK + f] = f2b(v.x);
            bs[(o0+1)*LDK + f] = f2b(v.y);
            bs[(o0+2)*LDK + f] = f2b(v.z);
            bs[(o0+3)*LDK + f] = f2b(v.w);
        }
    } else {
        #pragma unroll
        for (int k=0; k<8; k++){
            int q = tid + k*256;
            int o = q >> 5, f0 = (q & 31)*4;
            float sx=0.f, sy=0.f, sz=0.f, sw=0.f;
            #pragma unroll
            for (int hh=0; hh<8; hh++){
                float4 v = *(const float4*)(skip_w + (size_t)(hh*64+o)*FIN + f0);
                sx += v.x; sy += v.y; sz += v.z; sw += v.w;
            }
            ushort4 u = make_ushort4(f2b(sx*0.125f), f2b(sy*0.125f),
                                     f2b(sz*0.125f), f2b(sw*0.125f));
            *(ushort4*)(bs + o*LDK + f0) = u;
        }
    }
    __syncthreads();

    int lane = tid & 63, w = tid >> 6;
    int r16 = lane & 15, kg = lane >> 4;
    f32x4 acc[4] = {{0.f,0.f,0.f,0.f},{0.f,0.f,0.f,0.f},
                    {0.f,0.f,0.f,0.f},{0.f,0.f,0.f,0.f}};
    const ushort* arow = xs + (w*16 + r16)*LDK + kg*8;
    #pragma unroll
    for (int ks=0; ks<4; ks++){
        bf16x8 a = *(const bf16x8*)(arow + ks*32);
        #pragma unroll
        for (int ct=0; ct<4; ct++){
            bf16x8 b = *(const bf16x8*)(bs + (ct*16 + r16)*LDK + ks*32 + kg*8);
            acc[ct] = __builtin_amdgcn_mfma_f32_16x16x32_bf16(a, b, acc[ct], 0, 0, 0);
        }
    }

    int rowbase = n0 + w*16 + kg*4;
    if (h < 8){
        float as[4], at[4];
        #pragma unroll
        for (int ct=0; ct<4; ct++){
            as[ct] = a_src[h*64 + ct*16 + r16];
            at[ct] = a_tgt[h*64 + ct*16 + r16];
        }
        ushort* pbu = (ushort*)pb;
        #pragma unroll
        for (int r=0; r<4; r++){
            float vs = 0.f, vt = 0.f;
            #pragma unroll
            for (int ct=0; ct<4; ct++){
                float v = acc[ct][r];
                vs = fmaf(v, as[ct], vs);
                vt = fmaf(v, at[ct], vt);
                pbu[(size_t)(rowbase+r)*C_TOT + (ct*16 + r16)*8 + h] = f2b(v);
            }
            #pragma unroll
            for (int off=1; off<16; off<<=1){
                vs += __shfl_xor(vs, off);
                vt += __shfl_xor(vt, off);
            }
            if (r16 == 0){
                s_src_t[(size_t)(rowbase+r)*8 + h] = vs;
                s_tgt_t[(size_t)(rowbase+r)*8 + h] = vt;
            }
        }
    } else {
        #pragma unroll
        for (int r=0; r<4; r++)
            #pragma unroll
            for (int ct=0; ct<4; ct++)
                skipbar[(size_t)(rowbase+r)*FOUT + ct*16 + r16] = acc[ct][r];
    }
}

// ---------------------------------------------------------------------------
// Kernel 2: fused edge-extract + softmax + aggregation.
//   One wave per node, zero __syncthreads. Hot loop is LDS-FREE:
//   w and j live in the owning lane's registers; per-edge broadcast via
//   v_readlane into SGPRs (uniform loop counter), gather address is
//   SGPR-base + lane*16.
// ---------------------------------------------------------------------------
__global__ __launch_bounds__(256) void k_fused(const float* __restrict__ topo,
        const __hip_bfloat16* __restrict__ pb, const float* __restrict__ s_src_t,
        const float* __restrict__ s_tgt_t, const float* __restrict__ skipbar,
        float* __restrict__ out){
    __shared__ ushort jlds[4*ECAP];           // 1.5 KB, per-wave edge cols

    int lane = threadIdx.x & 63, w = threadIdx.x >> 6;
    int i    = blockIdx.x*4 + w;
    ushort* jp = jlds + w*ECAP;

    // ---- phase A: stream topology row, build 64-bit edge mask ------------
    const fx4* tp = (const fx4*)(topo + (size_t)i*N_NODES);
    unsigned long long m = 0;
    #pragma unroll
    for (int k=0; k<16; k++){
        fx4 v = __builtin_nontemporal_load(&tp[k*64 + lane]);
        unsigned b = 0;
        b |= (v.x==0.f) ? 1u : 0u;
        b |= (v.y==0.f) ? 2u : 0u;
        b |= (v.z==0.f) ? 4u : 0u;
        b |= (v.w==0.f) ? 8u : 0u;
        m |= ((unsigned long long)b) << (k*4);
    }

    // ---- phase B: lane prefix scan + compaction into LDS -----------------
    int cnt = __popcll(m);
    int pre = cnt;
    #pragma unroll
    for (int off=1; off<64; off<<=1){
        int t = __shfl_up(pre, off);
        if (lane >= off) pre += t;
    }
    int ne = __shfl(pre, 63);
    if (ne > ECAP) ne = ECAP;
    {
        int base = pre - cnt;
        unsigned long long mm = m;
        while (mm){
            int b = __builtin_ctzll(mm);
            mm &= mm - 1;
            if (base < ECAP)
                jp[base] = (ushort)((b>>2)*256 + lane*4 + (b&3));
            base++;
        }
    }
    // wave-synchronous LDS write->read within the same wave

    // ---- phase C: softmax stats; j and w stay in REGISTERS ---------------
    float4 ss0 = *(const float4*)(s_src_t + (size_t)i*8);
    float4 ss1 = *(const float4*)(s_src_t + (size_t)i*8 + 4);
    float ssrc[8] = {ss0.x,ss0.y,ss0.z,ss0.w,ss1.x,ss1.y,ss1.z,ss1.w};

    int   jreg[3];
    float st[3][8];
    #pragma unroll
    for (int s=0; s<3; s++){
        int e = s*64 + lane;
        bool act = e < ne;
        int j = act ? (int)jp[e] : 0;
        jreg[s] = j;
        const float4* tpp = (const float4*)(s_tgt_t + (size_t)j*8);
        float4 a = tpp[0], b = tpp[1];
        st[s][0] = act ? a.x : -3.0e38f;
        st[s][1] = act ? a.y : -3.0e38f;
        st[s][2] = act ? a.z : -3.0e38f;
        st[s][3] = act ? a.w : -3.0e38f;
        st[s][4] = act ? b.x : -3.0e38f;
        st[s][5] = act ? b.y : -3.0e38f;
        st[s][6] = act ? b.z : -3.0e38f;
        st[s][7] = act ? b.w : -3.0e38f;
    }
    float M[8];
    #pragma unroll
    for (int hh=0; hh<8; hh++)
        M[hh] = fmaxf(fmaxf(st[0][hh], st[1][hh]), st[2][hh]);
    #pragma unroll
    for (int off=32; off; off>>=1)
        #pragma unroll
        for (int hh=0; hh<8; hh++)
            M[hh] = fmaxf(M[hh], __shfl_xor(M[hh], off));
    #pragma unroll
    for (int hh=0; hh<8; hh++)
        M[hh] = lrelu(ssrc[hh] + M[hh]);

    float den[8] = {0.f,0.f,0.f,0.f,0.f,0.f,0.f,0.f};
    float wreg[3][8];
    #pragma unroll
    for (int s=0; s<3; s++){
        int e = s*64 + lane;
        bool act = e < ne;
        #pragma unroll
        for (int hh=0; hh<8; hh++){
            float z = ssrc[hh] + st[s][hh];
            z = z > 0.f ? z : 0.2f*z;
            float ww = __expf(z - M[hh]);
            ww = act ? ww : 0.f;
            den[hh] += ww;
            wreg[s][hh] = ww;
        }
    }
    #pragma unroll
    for (int off=32; off; off>>=1)
        #pragma unroll
        for (int hh=0; hh<8; hh++)
            den[hh] += __shfl_xor(den[hh], off);

    // ---- phase D: LDS-free gather-accumulate -----------------------------
    float acc[8] = {0.f,0.f,0.f,0.f,0.f,0.f,0.f,0.f};
    const char* pbb = (const char*)pb;
    #pragma unroll
    for (int s=0; s<3; s++){
        int nn = ne - s*64;
        nn = nn < 0 ? 0 : (nn > 64 ? 64 : nn);
        #pragma unroll 2
        for (int ee=0; ee<nn; ee++){
            int   j  = __builtin_amdgcn_readlane(jreg[s], ee);   // SGPR
            float w0 = rdlane(wreg[s][0], ee);                   // SGPRs
            float w1 = rdlane(wreg[s][1], ee);
            float w2 = rdlane(wreg[s][2], ee);
            float w3 = rdlane(wreg[s][3], ee);
            float w4 = rdlane(wreg[s][4], ee);
            float w5 = rdlane(wreg[s][5], ee);
            float w6 = rdlane(wreg[s][6], ee);
            float w7 = rdlane(wreg[s][7], ee);
            const uint4* row = (const uint4*)(pbb + ((size_t)(uint)j << 10));
            uint4 d = row[lane];             // SGPR base + lane*16 voffset
            acc[0] = fmaf(w0, __uint_as_float(d.x << 16), acc[0]);
            acc[1] = fmaf(w1, __uint_as_float(d.x),       acc[1]);
            acc[2] = fmaf(w2, __uint_as_float(d.y << 16), acc[2]);
            acc[3] = fmaf(w3, __uint_as_float(d.y),       acc[3]);
            acc[4] = fmaf(w4, __uint_as_float(d.z << 16), acc[4]);
            acc[5] = fmaf(w5, __uint_as_float(d.z),       acc[5]);
            acc[6] = fmaf(w6, __uint_as_float(d.w << 16), acc[6]);
            acc[7] = fmaf(w7, __uint_as_float(d.w),       acc[7]);
        }
    }

    // ---- head mean + skip + lrelu ----------------------------------------
    float s = 0.f;
    #pragma unroll
    for (int hh=0; hh<8; hh++) s += acc[hh] / den[hh];
    float o = s*0.125f + skipbar[(size_t)i*64 + lane];
    out[(size_t)i*64 + lane] = lrelu(o);
}

// ---------------------------------------------------------------------------
extern "C" void kernel_launch(void* const* d_in, const int* in_sizes, int n_in,
                              void* d_out, int out_size, void* d_ws, size_t ws_size,
                              hipStream_t stream){
    const float* x      = (const float*)d_in[0];
    const float* topo   = (const float*)d_in[1];
    const float* proj   = (const float*)d_in[2];
    const float* a_src  = (const float*)d_in[3];
    const float* a_tgt  = (const float*)d_in[4];
    const float* skip_w = (const float*)d_in[5];
    float* out = (float*)d_out;

    char* ws = (char*)d_ws;
    __hip_bfloat16* pb = (__hip_bfloat16*)ws;                 // 4 MB
    float*  skipbar = (float*)(ws + (4u<<20));                // 1 MB
    float*  s_src_t = (float*)(ws + (5u<<20));                // 128 KB
    float*  s_tgt_t = (float*)(ws + (5u<<20) + (128u<<10));   // 128 KB

    hipLaunchKernelGGL(k_gemm,  dim3(64, 9), dim3(256), 0, stream, x, proj, skip_w,
                       a_src, a_tgt, pb, s_src_t, s_tgt_t, skipbar);
    hipLaunchKernelGGL(k_fused, dim3(1024),  dim3(256), 0, stream, topo, pb,
                       s_src_t, s_tgt_t, skipbar, out);
}

// Round 9
// 47.994 us; speedup vs baseline: 1.3243x; 1.3243x over previous
//
#include <hip/hip_runtime.h>
#include <hip/hip_bf16.h>
#include <cstdint>

#define N_NODES 4096
#define FIN     128
#define FOUT    64
#define NHEAD   8
#define C_TOT   512   // NHEAD*FOUT
#define ECAP    192   // per-row edge capacity (= 3*64; mean deg ~82, sigma ~9)
#define LDK     136   // padded K-stride (bf16 elems)

typedef float fx4    __attribute__((ext_vector_type(4)));
typedef short bf16x8 __attribute__((ext_vector_type(8)));
typedef float f32x4  __attribute__((ext_vector_type(4)));

__device__ __forceinline__ float lrelu(float v){ return v > 0.f ? v : 0.2f*v; }

__device__ __forceinline__ ushort f2b(float f){
    uint u = __float_as_uint(f);
    return (ushort)((u + 0x7FFFu + ((u >> 16) & 1u)) >> 16);
}

// ---------------------------------------------------------------------------
// Kernel 1: MFMA bf16 GEMM (R6-proven). grid (64, 9), 256 thr (4 waves).
//   y = 0..7 : p-head GEMM + svec epilogue + bf16 head-minor store pb[n][c][h]
//   y = 8    : skip GEMM with inline head-averaged skip_w (f32 out, stride 64)
// ---------------------------------------------------------------------------
__global__ __launch_bounds__(256) void k_gemm(const float* __restrict__ x,
        const float* __restrict__ proj, const float* __restrict__ skip_w,
        const float* __restrict__ a_src, const float* __restrict__ a_tgt,
        __hip_bfloat16* __restrict__ pb, float* __restrict__ s_src_t,
        float* __restrict__ s_tgt_t, float* __restrict__ skipbar){
    __shared__ ushort xs[64*LDK];   // A tile
    __shared__ ushort bs[64*LDK];   // B^T tile
    int tid = threadIdx.x;
    int n0  = blockIdx.x * 64;
    int h   = blockIdx.y;

    #pragma unroll
    for (int k=0; k<8; k++){
        int q = tid + k*256;
        int r = q >> 5, f0 = (q & 31)*4;
        float4 v = *(const float4*)(x + (size_t)(n0+r)*FIN + f0);
        ushort4 u = make_ushort4(f2b(v.x), f2b(v.y), f2b(v.z), f2b(v.w));
        *(ushort4*)(xs + r*LDK + f0) = u;
    }
    if (h < 8){
        const float* B = proj + (size_t)h*FIN*FOUT;
        #pragma unroll
        for (int k=0; k<8; k++){
            int q = tid + k*256;
            int f = q >> 4, o0 = (q & 15)*4;
            float4 v = *(const float4*)(B + f*64 + o0);
            bs[(o0+0)*LDK + f] = f2b(v.x);
            bs[(o0+1)*LDK + f] = f2b(v.y);
            bs[(o0+2)*LDK + f] = f2b(v.z);
            bs[(o0+3)*LDK + f] = f2b(v.w);
        }
    } else {
        #pragma unroll
        for (int k=0; k<8; k++){
            int q = tid + k*256;
            int o = q >> 5, f0 = (q & 31)*4;
            float sx=0.f, sy=0.f, sz=0.f, sw=0.f;
            #pragma unroll
            for (int hh=0; hh<8; hh++){
                float4 v = *(const float4*)(skip_w + (size_t)(hh*64+o)*FIN + f0);
                sx += v.x; sy += v.y; sz += v.z; sw += v.w;
            }
            ushort4 u = make_ushort4(f2b(sx*0.125f), f2b(sy*0.125f),
                                     f2b(sz*0.125f), f2b(sw*0.125f));
            *(ushort4*)(bs + o*LDK + f0) = u;
        }
    }
    __syncthreads();

    int lane = tid & 63, w = tid >> 6;
    int r16 = lane & 15, kg = lane >> 4;
    f32x4 acc[4] = {{0.f,0.f,0.f,0.f},{0.f,0.f,0.f,0.f},
                    {0.f,0.f,0.f,0.f},{0.f,0.f,0.f,0.f}};
    const ushort* arow = xs + (w*16 + r16)*LDK + kg*8;
    #pragma unroll
    for (int ks=0; ks<4; ks++){
        bf16x8 a = *(const bf16x8*)(arow + ks*32);
        #pragma unroll
        for (int ct=0; ct<4; ct++){
            bf16x8 b = *(const bf16x8*)(bs + (ct*16 + r16)*LDK + ks*32 + kg*8);
            acc[ct] = __builtin_amdgcn_mfma_f32_16x16x32_bf16(a, b, acc[ct], 0, 0, 0);
        }
    }

    int rowbase = n0 + w*16 + kg*4;
    if (h < 8){
        float as[4], at[4];
        #pragma unroll
        for (int ct=0; ct<4; ct++){
            as[ct] = a_src[h*64 + ct*16 + r16];
            at[ct] = a_tgt[h*64 + ct*16 + r16];
        }
        ushort* pbu = (ushort*)pb;
        #pragma unroll
        for (int r=0; r<4; r++){
            float vs = 0.f, vt = 0.f;
            #pragma unroll
            for (int ct=0; ct<4; ct++){
                float v = acc[ct][r];
                vs = fmaf(v, as[ct], vs);
                vt = fmaf(v, at[ct], vt);
                pbu[(size_t)(rowbase+r)*C_TOT + (ct*16 + r16)*8 + h] = f2b(v);
            }
            #pragma unroll
            for (int off=1; off<16; off<<=1){
                vs += __shfl_xor(vs, off);
                vt += __shfl_xor(vt, off);
            }
            if (r16 == 0){
                s_src_t[(size_t)(rowbase+r)*8 + h] = vs;
                s_tgt_t[(size_t)(rowbase+r)*8 + h] = vt;
            }
        }
    } else {
        #pragma unroll
        for (int r=0; r<4; r++)
            #pragma unroll
            for (int ct=0; ct<4; ct++)
                skipbar[(size_t)(rowbase+r)*FOUT + ct*16 + r16] = acc[ct][r];
    }
}

// ---------------------------------------------------------------------------
// Kernel 2: fused edge-extract + softmax + aggregation.
//   One wave per node, zero __syncthreads.
//   Phase D: 8-edge batches — 8 independent VGPR-addressed dwordx4 gathers in
//   flight per wave (128/CU), j/w broadcast from per-wave LDS strips, tail
//   zero-padded so the hot loop is branch-free.
// ---------------------------------------------------------------------------
__global__ __launch_bounds__(256) void k_fused(const float* __restrict__ topo,
        const __hip_bfloat16* __restrict__ pb, const float* __restrict__ s_src_t,
        const float* __restrict__ s_tgt_t, const float* __restrict__ skipbar,
        float* __restrict__ out){
    __shared__ float  wlds[4*ECAP*8];         // 24 KB, per-wave w[e][h]
    __shared__ ushort jlds[4*ECAP];           // 1.5 KB, per-wave edge cols

    int lane = threadIdx.x & 63, w = threadIdx.x >> 6;
    int i    = blockIdx.x*4 + w;
    float*  wp = wlds + w*(ECAP*8);
    ushort* jp = jlds + w*ECAP;

    // zero-init edge list (tail slots must be safe j=0)
    jp[lane] = 0; jp[64+lane] = 0; jp[128+lane] = 0;

    // ---- phase A: stream topology row, build 64-bit edge mask ------------
    const fx4* tp = (const fx4*)(topo + (size_t)i*N_NODES);
    unsigned long long m = 0;
    #pragma unroll
    for (int k=0; k<16; k++){
        fx4 v = __builtin_nontemporal_load(&tp[k*64 + lane]);
        unsigned b = 0;
        b |= (v.x==0.f) ? 1u : 0u;
        b |= (v.y==0.f) ? 2u : 0u;
        b |= (v.z==0.f) ? 4u : 0u;
        b |= (v.w==0.f) ? 8u : 0u;
        m |= ((unsigned long long)b) << (k*4);
    }

    // ---- phase B: lane prefix scan + compaction into LDS -----------------
    int cnt = __popcll(m);
    int pre = cnt;
    #pragma unroll
    for (int off=1; off<64; off<<=1){
        int t = __shfl_up(pre, off);
        if (lane >= off) pre += t;
    }
    int ne = __shfl(pre, 63);
    if (ne > ECAP) ne = ECAP;
    {
        int base = pre - cnt;
        unsigned long long mm = m;
        while (mm){
            int b = __builtin_ctzll(mm);
            mm &= mm - 1;
            if (base < ECAP)
                jp[base] = (ushort)((b>>2)*256 + lane*4 + (b&3));
            base++;
        }
    }
    // wave-synchronous LDS write->read within the same wave

    // ---- phase C: softmax stats (in-register butterflies) ----------------
    float4 ss0 = *(const float4*)(s_src_t + (size_t)i*8);
    float4 ss1 = *(const float4*)(s_src_t + (size_t)i*8 + 4);
    float ssrc[8] = {ss0.x,ss0.y,ss0.z,ss0.w,ss1.x,ss1.y,ss1.z,ss1.w};

    float st[3][8];
    #pragma unroll
    for (int s=0; s<3; s++){
        int e = s*64 + lane;
        bool act = e < ne;
        int j = act ? (int)jp[e] : 0;
        const float4* tpp = (const float4*)(s_tgt_t + (size_t)j*8);
        float4 a = tpp[0], b = tpp[1];
        st[s][0] = act ? a.x : -3.0e38f;
        st[s][1] = act ? a.y : -3.0e38f;
        st[s][2] = act ? a.z : -3.0e38f;
        st[s][3] = act ? a.w : -3.0e38f;
        st[s][4] = act ? b.x : -3.0e38f;
        st[s][5] = act ? b.y : -3.0e38f;
        st[s][6] = act ? b.z : -3.0e38f;
        st[s][7] = act ? b.w : -3.0e38f;
    }
    float M[8];
    #pragma unroll
    for (int hh=0; hh<8; hh++)
        M[hh] = fmaxf(fmaxf(st[0][hh], st[1][hh]), st[2][hh]);
    #pragma unroll
    for (int off=32; off; off>>=1)
        #pragma unroll
        for (int hh=0; hh<8; hh++)
            M[hh] = fmaxf(M[hh], __shfl_xor(M[hh], off));
    #pragma unroll
    for (int hh=0; hh<8; hh++)
        M[hh] = lrelu(ssrc[hh] + M[hh]);

    // w -> LDS unconditionally (zeros for inactive slots -> branch-free D)
    float den[8] = {0.f,0.f,0.f,0.f,0.f,0.f,0.f,0.f};
    #pragma unroll
    for (int s=0; s<3; s++){
        int e = s*64 + lane;
        bool act = e < ne;
        float wv[8];
        #pragma unroll
        for (int hh=0; hh<8; hh++){
            float z = ssrc[hh] + st[s][hh];
            z = z > 0.f ? z : 0.2f*z;
            float ww = __expf(z - M[hh]);
            ww = act ? ww : 0.f;
            den[hh] += ww;
            wv[hh] = ww;
        }
        *(float4*)(wp + e*8)     = make_float4(wv[0],wv[1],wv[2],wv[3]);
        *(float4*)(wp + e*8 + 4) = make_float4(wv[4],wv[5],wv[6],wv[7]);
    }
    #pragma unroll
    for (int off=32; off; off>>=1)
        #pragma unroll
        for (int hh=0; hh<8; hh++)
            den[hh] += __shfl_xor(den[hh], off);

    // ---- phase D: 8-edge batched gather-accumulate -----------------------
    float acc[8] = {0.f,0.f,0.f,0.f,0.f,0.f,0.f,0.f};
    const char* pbb = (const char*)pb;
    uint laneoff = (uint)lane * 16;
    int ne8 = (ne + 7) & ~7;
    for (int e0=0; e0<ne8; e0+=8){
        int jj[8];
        #pragma unroll
        for (int k=0; k<8; k++) jj[k] = (int)jp[e0+k];        // LDS broadcast
        uint4 d[8];
        #pragma unroll
        for (int k=0; k<8; k++)                               // 8 loads in flight
            d[k] = *(const uint4*)(pbb + ((size_t)(uint)jj[k] << 10) + laneoff);
        #pragma unroll
        for (int k=0; k<8; k++){
            float4 wa = *(const float4*)(wp + (e0+k)*8);      // LDS broadcast
            float4 wb = *(const float4*)(wp + (e0+k)*8 + 4);
            acc[0] = fmaf(wa.x, __uint_as_float(d[k].x << 16), acc[0]);
            acc[1] = fmaf(wa.y, __uint_as_float(d[k].x),       acc[1]);
            acc[2] = fmaf(wa.z, __uint_as_float(d[k].y << 16), acc[2]);
            acc[3] = fmaf(wa.w, __uint_as_float(d[k].y),       acc[3]);
            acc[4] = fmaf(wb.x, __uint_as_float(d[k].z << 16), acc[4]);
            acc[5] = fmaf(wb.y, __uint_as_float(d[k].z),       acc[5]);
            acc[6] = fmaf(wb.z, __uint_as_float(d[k].w << 16), acc[6]);
            acc[7] = fmaf(wb.w, __uint_as_float(d[k].w),       acc[7]);
        }
    }

    // ---- head mean + skip + lrelu ----------------------------------------
    float s = 0.f;
    #pragma unroll
    for (int hh=0; hh<8; hh++) s += acc[hh] / den[hh];
    float o = s*0.125f + skipbar[(size_t)i*64 + lane];
    out[(size_t)i*64 + lane] = lrelu(o);
}

// ---------------------------------------------------------------------------
extern "C" void kernel_launch(void* const* d_in, const int* in_sizes, int n_in,
                              void* d_out, int out_size, void* d_ws, size_t ws_size,
                              hipStream_t stream){
    const float* x      = (const float*)d_in[0];
    const float* topo   = (const float*)d_in[1];
    const float* proj   = (const float*)d_in[2];
    const float* a_src  = (const float*)d_in[3];
    const float* a_tgt  = (const float*)d_in[4];
    const float* skip_w = (const float*)d_in[5];
    float* out = (float*)d_out;

    char* ws = (char*)d_ws;
    __hip_bfloat16* pb = (__hip_bfloat16*)ws;                 // 4 MB
    float*  skipbar = (float*)(ws + (4u<<20));                // 1 MB
    float*  s_src_t = (float*)(ws + (5u<<20));                // 128 KB
    float*  s_tgt_t = (float*)(ws + (5u<<20) + (128u<<10));   // 128 KB

    hipLaunchKernelGGL(k_gemm,  dim3(64, 9), dim3(256), 0, stream, x, proj, skip_w,
                       a_src, a_tgt, pb, s_src_t, s_tgt_t, skipbar);
    hipLaunchKernelGGL(k_fused, dim3(1024),  dim3(256), 0, stream, topo, pb,
                       s_src_t, s_tgt_t, skipbar, out);
}